// Round 7
// baseline (1643.169 us; speedup 1.0000x reference)
//
#include <hip/hip_runtime.h>
#include <hip/hip_fp16.h>

// ---------------------------------------------------------------------------
// 2-layer tanh RNN, B=256, T=512, H=512, D=64, + FC(512->1).
//   proj0:  P[b,t,:] = x[b,t,:] @ W_ih0^T + (b_ih0+b_hh0)     (MFMA f16, K=64)
//   rec0:   per-CU recurrence via M=1 MFMA, writes h1 in place over P
//   proj1:  P[b,t,:] = h1[b,t,:] @ W_ih1^T + (b_ih1+b_hh1)    (in-place)
//   rec1:   recurrence + final FC -> d_out[256]
//
// rec engine: one chain per CU, 512 threads = 8 waves = 2 waves/SIMD.
// ROUND-7 ISOLATION EXPERIMENT: R5/R6 failed correctness (~2e-2) with three
// coupled changes; tanh variant exonerated (R6). This round keeps the R4
// known-good MFMA machinery -- acc in VGPR ("+v"), pools 32 AGPR + 14 VGPR +
// 18 LDS frags per wave, NO global pool (its register funding required the
// suspect AGPR-acc) -- and adds ONLY the ring k-order + pre-barrier prework:
//   ring: wave w consumes kk=(2w+j)&15 at position j; j=0,1 cover the wave's
//   OWN h-slice [64w,64w+64) -> 8 of 64 MFMAs issued pre-barrier right after
//   the wave's own ds_write + lgkmcnt(0). Single top-of-loop barrier; hbuf
//   double-buffered and 2x replicated so ring A-addressing is wrap-free.
// Suspect under test next round if this passes: inline-asm MFMA with "+a" acc
// (opaque asm gets no MFMA->v_accvgpr_read wait states from the compiler).
// Per-wave frag pools (64 frags: (j,g), g=n-group 0..3):
//   AGPR 32: g<2 -> slot 2j+g          VGPR 14: g=2, j<14 -> breg_v[j]
//   LDS  18: g=3 -> slot j (0..15);  g=2, j>=14 -> slots 16,17
// ---------------------------------------------------------------------------

typedef _Float16 h2 __attribute__((ext_vector_type(2)));
typedef _Float16 h8 __attribute__((ext_vector_type(8)));
typedef float    f4 __attribute__((ext_vector_type(4)));

#define HID   512
#define TSEQ  512
#define NB    256
#define NWAVE 8
#define NRSL  46   // reg slots per wave: 32 AGPR + 14 VGPR
#define NLSL  18   // LDS slots per wave

// D = A*B + D; acc in VGPR ("+v", the R4 known-good path); B AGPR / VGPR.
#define MFMA_A(accv, av, bv) \
  asm("v_mfma_f32_16x16x32_f16 %0, %1, %2, %0" : "+v"(accv) : "v"(av), "a"(bv))
#define MFMA_V(accv, av, bv) \
  asm("v_mfma_f32_16x16x32_f16 %0, %1, %2, %0" : "+v"(accv) : "v"(av), "v"(bv))

// ---------------- workspace layout (bytes) ----------------
static const size_t OFF_P   = 0;                       // [131072][512] fp16  134217728
static const size_t OFF_B0  = 134217728;               // W_ih0 fp16 [512][64]    65536
static const size_t OFF_B1  = OFF_B0 + 65536;          // W_ih1 fp16 [512][512]  524288
static const size_t OFF_R0  = OFF_B1 + 524288;         // 8*46*64*16 = 376832
static const size_t OFF_L0  = OFF_R0 + 376832;         // 8*18*64*16 = 147456
static const size_t OFF_R1  = OFF_L0 + 147456;
static const size_t OFF_L1  = OFF_R1 + 376832;
static const size_t OFF_BS0 = OFF_L1 + 147456;         // bias0 f32 [512]
static const size_t OFF_BS1 = OFF_BS0 + 2048;          // bias1 f32 [512]

// ---------------- prep kernels ----------------
__global__ void bias_kernel(const float* __restrict__ bih0, const float* __restrict__ bhh0,
                            const float* __restrict__ bih1, const float* __restrict__ bhh1,
                            float* __restrict__ bias0, float* __restrict__ bias1) {
  int i = threadIdx.x;  // block 512
  bias0[i] = bih0[i] + bhh0[i];
  bias1[i] = bih1[i] + bhh1[i];
}

__global__ void cvt_half_kernel(const float* __restrict__ in, _Float16* __restrict__ outp, int n) {
  int i = blockIdx.x * 256 + threadIdx.x;
  if (i < n) outp[i] = (_Float16)in[i];
}

// Pack W_hh (fp32 [512][512]) into ring-ordered MFMA B-fragment pools.
// Fragment (wave w, n-group g, kstep kk), lane l:
//   8 halfs = W[64w + 16g + (l&15)][32kk + (l>>4)*8 .. +8);  j = (kk-2w) mod 16.
__global__ void pack_rec_kernel(const float* __restrict__ W, uint4* __restrict__ BregP,
                                uint4* __restrict__ BldsP) {
  int t = blockIdx.x * 256 + threadIdx.x;   // 32768 threads
  int l  = t & 63;
  int g  = (t >> 6) & 3;
  int kk = (t >> 8) & 15;
  int w  = (t >> 12) & 7;
  int j  = (kk - 2 * w) & 15;
  int n  = 64 * w + 16 * g + (l & 15);
  int k0 = 32 * kk + ((l >> 4) & 3) * 8;
  const float* src = W + (size_t)n * HID + k0;
  h8 v;
#pragma unroll
  for (int i = 0; i < 8; ++i) v[i] = (_Float16)src[i];
  uint4 u = __builtin_bit_cast(uint4, v);
  if (g < 2) {
    BregP[(w * NRSL + 2 * j + g) * 64 + l] = u;
  } else if (g == 2) {
    if (j < 14) BregP[(w * NRSL + 32 + j) * 64 + l] = u;
    else        BldsP[(w * NLSL + 16 + (j - 14)) * 64 + l] = u;
  } else {
    BldsP[(w * NLSL + j) * 64 + l] = u;
  }
}

// ---------------- projection GEMM (MFMA f16) ----------------
template <typename AT, int K>
__global__ __launch_bounds__(256, 2) void proj_kernel(const AT* A, const _Float16* __restrict__ Bw,
                                                      _Float16* C, const float* __restrict__ bias) {
  __shared__ _Float16 At[64][40];
  __shared__ _Float16 Bt[512][40];
  const int tid = threadIdx.x;
  const int m0 = blockIdx.x * 64;
  const int wv = tid >> 6;
  const int l = tid & 63;
  const int n0 = wv * 128;
  const int lm = l & 15;
  const int lq = l >> 4;

  f4 acc[4][8];
#pragma unroll
  for (int i = 0; i < 4; ++i)
#pragma unroll
    for (int j = 0; j < 8; ++j) acc[i][j] = (f4){0.f, 0.f, 0.f, 0.f};

  const int arow = tid >> 2;
  const int kq = (tid & 3) * 8;

  for (int k0 = 0; k0 < K; k0 += 32) {
    if (sizeof(AT) == 4) {
      const float* ap = (const float*)A + (size_t)(m0 + arow) * K + k0 + kq;
      h8 v;
#pragma unroll
      for (int i = 0; i < 8; ++i) v[i] = (_Float16)ap[i];
      *(h8*)&At[arow][kq] = v;
    } else {
      *(h8*)&At[arow][kq] = *(const h8*)((const _Float16*)A + (size_t)(m0 + arow) * K + k0 + kq);
    }
#pragma unroll
    for (int rr = 0; rr < 8; ++rr) {
      int rrow = arow + rr * 64;
      *(h8*)&Bt[rrow][kq] = *(const h8*)(Bw + (size_t)rrow * K + k0 + kq);
    }
    __syncthreads();
    h8 af[4];
#pragma unroll
    for (int mm = 0; mm < 4; ++mm) af[mm] = *(const h8*)&At[mm * 16 + lm][lq * 8];
#pragma unroll
    for (int nn = 0; nn < 8; ++nn) {
      h8 bf = *(const h8*)&Bt[n0 + nn * 16 + lm][lq * 8];
#pragma unroll
      for (int mm = 0; mm < 4; ++mm)
        acc[mm][nn] = __builtin_amdgcn_mfma_f32_16x16x32_f16(af[mm], bf, acc[mm][nn], 0, 0, 0);
    }
    __syncthreads();
  }
#pragma unroll
  for (int nn = 0; nn < 8; ++nn) {
    int col = n0 + nn * 16 + lm;
    float bv = bias[col];
#pragma unroll
    for (int mm = 0; mm < 4; ++mm) {
#pragma unroll
      for (int r = 0; r < 4; ++r) {
        int row = m0 + mm * 16 + lq * 4 + r;
        C[(size_t)row * HID + col] = (_Float16)(acc[mm][nn][r] + bv);
      }
    }
  }
}

// ---------------- recurrence kernel (ring order, VGPR acc) ----------------
template <bool WRITE_H, bool DO_FC>
__global__ __launch_bounds__(512, 2) void rec_kernel(
    const _Float16* __restrict__ P, _Float16* __restrict__ Pout,
    const uint4* __restrict__ BregP, const uint4* __restrict__ BldsP,
    const float* __restrict__ Wfc, const float* __restrict__ bfc, float* __restrict__ out) {
  __shared__ __align__(16) uint4 Blds[NWAVE * NLSL * 64];   // 147456 B
  __shared__ __align__(16) _Float16 hbuf2[2][2 * HID];      // 4 KB, double-buffered, 2x replicated
  __shared__ __align__(16) float hxch[NWAVE][64];           // 2 KB, per-wave private
  __shared__ float red[NWAVE];
  const int tid = threadIdx.x;
  const int b = blockIdx.x;
  const int w = tid >> 6, l = tid & 63, lq = l >> 4;

  // one-time loads: breg_a consumed only as asm "a" -> AGPR; breg_v as "v" -> VGPR.
  h8 breg_a[32];
#pragma unroll
  for (int i = 0; i < 32; ++i)
    breg_a[i] = __builtin_bit_cast(h8, BregP[(w * NRSL + i) * 64 + l]);
  h8 breg_v[14];
#pragma unroll
  for (int i = 0; i < 14; ++i)
    breg_v[i] = __builtin_bit_cast(h8, BregP[(w * NRSL + 32 + i) * 64 + l]);
  const uint4* bl = &Blds[w * NLSL * 64 + l];        // slot s at bl[s*64]
#pragma unroll
  for (int s = 0; s < NLSL; ++s)
    Blds[(w * NLSL + s) * 64 + l] = BldsP[(w * NLSL + s) * 64 + l];

  hbuf2[0][tid] = (_Float16)0.f;          // h0 = 0, both replicas
  hbuf2[0][tid + 512] = (_Float16)0.f;
  __syncthreads();

  const _Float16* prow = P + (size_t)b * TSEQ * HID;
  _Float16* pw = WRITE_H ? (Pout + (size_t)b * TSEQ * HID + tid) : nullptr;
  unsigned short xp_cur = *(const unsigned short*)(prow + tid);
  const int abase = 64 * w + 8 * lq;     // halfs; A-frag j at hb + abase + 32*j
  float lv = 0.f;

  f4 acc0, acc1, acc2, acc3;

  // ---- prologue: prework for t=0 (h0 = 0, so j=0,1 MFMAs produce zeros) ----
  acc0 = (f4){0.f, 0.f, 0.f, 0.f}; acc1 = acc0; acc2 = acc0; acc3 = acc0;
  {
    const _Float16* hbn = hbuf2[0];
    h8 A0 = *(const h8*)(hbn + abase);
    h8 A1 = *(const h8*)(hbn + abase + 32);
    h8 bf0 = __builtin_bit_cast(h8, bl[0 * 64]);
    h8 bf1 = __builtin_bit_cast(h8, bl[1 * 64]);
    MFMA_A(acc0, A0, breg_a[0]); MFMA_A(acc1, A0, breg_a[1]);
    MFMA_V(acc2, A0, breg_v[0]); MFMA_V(acc3, A0, bf0);
    MFMA_A(acc0, A1, breg_a[2]); MFMA_A(acc1, A1, breg_a[3]);
    MFMA_V(acc2, A1, breg_v[1]); MFMA_V(acc3, A1, bf1);
  }

#pragma unroll 1
  for (int t = 0; t < TSEQ; ++t) {
    __syncthreads();   // all waves' h(t) published (j=0,1 already accumulated)
    int tn = (t + 1 < TSEQ) ? t + 1 : t;
    unsigned short xp_next = *(const unsigned short*)(prow + (size_t)tn * HID + tid);
    const _Float16* hb = hbuf2[t & 1];

#define AFRAG(J) (*(const h8*)(hb + abase + 32 * (J)))
#define LDSF(S) __builtin_bit_cast(h8, bl[(S) * 64])
    // j = 2..13: g2 from VGPR breg_v[j], g3 from LDS slot j
    { h8 A = AFRAG(2);  MFMA_A(acc0, A, breg_a[4]);  MFMA_A(acc1, A, breg_a[5]);
      MFMA_V(acc2, A, breg_v[2]);  h8 bf = LDSF(2);  MFMA_V(acc3, A, bf); }
    { h8 A = AFRAG(3);  MFMA_A(acc0, A, breg_a[6]);  MFMA_A(acc1, A, breg_a[7]);
      MFMA_V(acc2, A, breg_v[3]);  h8 bf = LDSF(3);  MFMA_V(acc3, A, bf); }
    { h8 A = AFRAG(4);  MFMA_A(acc0, A, breg_a[8]);  MFMA_A(acc1, A, breg_a[9]);
      MFMA_V(acc2, A, breg_v[4]);  h8 bf = LDSF(4);  MFMA_V(acc3, A, bf); }
    { h8 A = AFRAG(5);  MFMA_A(acc0, A, breg_a[10]); MFMA_A(acc1, A, breg_a[11]);
      MFMA_V(acc2, A, breg_v[5]);  h8 bf = LDSF(5);  MFMA_V(acc3, A, bf); }
    { h8 A = AFRAG(6);  MFMA_A(acc0, A, breg_a[12]); MFMA_A(acc1, A, breg_a[13]);
      MFMA_V(acc2, A, breg_v[6]);  h8 bf = LDSF(6);  MFMA_V(acc3, A, bf); }
    { h8 A = AFRAG(7);  MFMA_A(acc0, A, breg_a[14]); MFMA_A(acc1, A, breg_a[15]);
      MFMA_V(acc2, A, breg_v[7]);  h8 bf = LDSF(7);  MFMA_V(acc3, A, bf); }
    { h8 A = AFRAG(8);  MFMA_A(acc0, A, breg_a[16]); MFMA_A(acc1, A, breg_a[17]);
      MFMA_V(acc2, A, breg_v[8]);  h8 bf = LDSF(8);  MFMA_V(acc3, A, bf); }
    { h8 A = AFRAG(9);  MFMA_A(acc0, A, breg_a[18]); MFMA_A(acc1, A, breg_a[19]);
      MFMA_V(acc2, A, breg_v[9]);  h8 bf = LDSF(9);  MFMA_V(acc3, A, bf); }
    { h8 A = AFRAG(10); MFMA_A(acc0, A, breg_a[20]); MFMA_A(acc1, A, breg_a[21]);
      MFMA_V(acc2, A, breg_v[10]); h8 bf = LDSF(10); MFMA_V(acc3, A, bf); }
    { h8 A = AFRAG(11); MFMA_A(acc0, A, breg_a[22]); MFMA_A(acc1, A, breg_a[23]);
      MFMA_V(acc2, A, breg_v[11]); h8 bf = LDSF(11); MFMA_V(acc3, A, bf); }
    { h8 A = AFRAG(12); MFMA_A(acc0, A, breg_a[24]); MFMA_A(acc1, A, breg_a[25]);
      MFMA_V(acc2, A, breg_v[12]); h8 bf = LDSF(12); MFMA_V(acc3, A, bf); }
    { h8 A = AFRAG(13); MFMA_A(acc0, A, breg_a[26]); MFMA_A(acc1, A, breg_a[27]);
      MFMA_V(acc2, A, breg_v[13]); h8 bf = LDSF(13); MFMA_V(acc3, A, bf); }
    // j = 14,15: g2 from LDS slots 16,17, g3 from LDS slots 14,15
    { h8 A = AFRAG(14); MFMA_A(acc0, A, breg_a[28]); MFMA_A(acc1, A, breg_a[29]);
      h8 b2 = LDSF(16); MFMA_V(acc2, A, b2); h8 b3 = LDSF(14); MFMA_V(acc3, A, b3); }
    { h8 A = AFRAG(15); MFMA_A(acc0, A, breg_a[30]); MFMA_A(acc1, A, breg_a[31]);
      h8 b2 = LDSF(17); MFMA_V(acc2, A, b2); h8 b3 = LDSF(15); MFMA_V(acc3, A, b3); }
#undef AFRAG
#undef LDSF

    // extraction: lanes<16 hold n=64w+16g+l in acc{g}[0] (all D rows equal)
    if (l < 16) {
      hxch[w][l]      = acc0[0];
      hxch[w][16 + l] = acc1[0];
      hxch[w][32 + l] = acc2[0];
      hxch[w][48 + l] = acc3[0];
    }
    asm volatile("s_waitcnt lgkmcnt(0)" ::: "memory");
    float hr = hxch[w][l];   // n = 64w + l = tid

    float v = tanhf(hr + (float)__builtin_bit_cast(_Float16, xp_cur));
    lv = v;
    _Float16 hw = (_Float16)v;
    _Float16* hbn = hbuf2[(t + 1) & 1];
    hbn[tid] = hw;
    hbn[tid + 512] = hw;
    if (WRITE_H) pw[(size_t)t * HID] = hw;
    asm volatile("s_waitcnt lgkmcnt(0)" ::: "memory");   // own slice visible to own reads

    // ---- prework for step t+1 (pre-barrier: own-slice j=0,1) ----
    acc0 = (f4){0.f, 0.f, 0.f, 0.f}; acc1 = acc0; acc2 = acc0; acc3 = acc0;
    {
      h8 A0 = *(const h8*)(hbn + abase);
      h8 A1 = *(const h8*)(hbn + abase + 32);
      h8 bf0 = __builtin_bit_cast(h8, bl[0 * 64]);
      h8 bf1 = __builtin_bit_cast(h8, bl[1 * 64]);
      MFMA_A(acc0, A0, breg_a[0]); MFMA_A(acc1, A0, breg_a[1]);
      MFMA_V(acc2, A0, breg_v[0]); MFMA_V(acc3, A0, bf0);
      MFMA_A(acc0, A1, breg_a[2]); MFMA_A(acc1, A1, breg_a[3]);
      MFMA_V(acc2, A1, breg_v[1]); MFMA_V(acc3, A1, bf1);
    }
    xp_cur = xp_next;
  }

  if (DO_FC) {
    float fc = lv * Wfc[tid];
#pragma unroll
    for (int off = 32; off; off >>= 1) fc += __shfl_down(fc, off, 64);
    if (l == 0) red[w] = fc;
    __syncthreads();
    if (tid == 0) {
      float s = bfc[0];
#pragma unroll
      for (int i = 0; i < NWAVE; ++i) s += red[i];
      out[b] = s;
    }
  }
}

// ---------------- launcher ----------------
extern "C" void kernel_launch(void* const* d_in, const int* in_sizes, int n_in,
                              void* d_out, int out_size, void* d_ws, size_t ws_size,
                              hipStream_t stream) {
  const float* x    = (const float*)d_in[0];
  const float* Wih0 = (const float*)d_in[1];
  const float* Whh0 = (const float*)d_in[2];
  const float* bih0 = (const float*)d_in[3];
  const float* bhh0 = (const float*)d_in[4];
  const float* Wih1 = (const float*)d_in[5];
  const float* Whh1 = (const float*)d_in[6];
  const float* bih1 = (const float*)d_in[7];
  const float* bhh1 = (const float*)d_in[8];
  const float* Wfc  = (const float*)d_in[9];
  const float* bfc  = (const float*)d_in[10];
  float* out = (float*)d_out;
  char* ws = (char*)d_ws;

  _Float16* P  = (_Float16*)(ws + OFF_P);
  _Float16* B0 = (_Float16*)(ws + OFF_B0);
  _Float16* B1 = (_Float16*)(ws + OFF_B1);
  uint4* R0 = (uint4*)(ws + OFF_R0);
  uint4* L0 = (uint4*)(ws + OFF_L0);
  uint4* R1 = (uint4*)(ws + OFF_R1);
  uint4* L1 = (uint4*)(ws + OFF_L1);
  float* bias0 = (float*)(ws + OFF_BS0);
  float* bias1 = (float*)(ws + OFF_BS1);

  bias_kernel<<<1, 512, 0, stream>>>(bih0, bhh0, bih1, bhh1, bias0, bias1);
  cvt_half_kernel<<<128, 256, 0, stream>>>(Wih0, B0, 512 * 64);
  cvt_half_kernel<<<1024, 256, 0, stream>>>(Wih1, B1, 512 * 512);
  pack_rec_kernel<<<128, 256, 0, stream>>>(Whh0, R0, L0);
  pack_rec_kernel<<<128, 256, 0, stream>>>(Whh1, R1, L1);

  proj_kernel<float, 64><<<2048, 256, 0, stream>>>(x, B0, P, bias0);
  rec_kernel<true, false><<<NB, 512, 0, stream>>>(P, P, R0, L0, nullptr, nullptr, nullptr);
  proj_kernel<_Float16, 512><<<2048, 256, 0, stream>>>(P, B1, P, bias1);
  rec_kernel<false, true><<<NB, 512, 0, stream>>>(P, nullptr, R1, L1, Wfc, bfc, out);
}